// Round 15
// baseline (184.929 us; speedup 1.0000x reference)
//
#include <hip/hip_runtime.h>

#define N_NODES 100000
#define N_EDGES 3200000
#define NB 768                         // buckets: exactly 3 per CU
#define BKN 131                        // nodes per bucket (768*131=100608)
#define RSZ 5120                       // per-bucket record window (mean 4167)
#define TILE 6250
#define NTILES 512                     // 512*6250 == 3.2M exactly; 2 blocks/CU
#define PRJ_PER_BLOCK 196              // 512*196 = 100352 >= N_NODES
#define MAXIT 13                       // ceil(TILE/512)
#define MAXB 10                        // ceil(RSZ/512)

// ---------------------------------------------------------------------------
// Workspace layout (4-byte elements):
//   gcur      NB*16 ints (relative cursor/bucket, one per 64B line; memset 0)
//   node_off  100608     (absolute start of node's run in recs, global n idx)
//   node_cnt  100608     (in-degree per node, global n idx)
//   recs      NB*RSZ     (pass A: (local_dst<<17)|src bucket-grouped;
//                         pass B: sortagg1 overwrites with node-sorted src)
//   p1h   16N ushorts = bf16(x @ Wl1^T)   (3.2 MB, L2-resident)
//   q1b   16N floats  = x @ Wr1^T + b1
//   p2 / r2 / deg_inv   N floats each
// ---------------------------------------------------------------------------

__device__ __forceinline__ float bf2f_lo(unsigned int w) {
  return __uint_as_float(w << 16);
}
__device__ __forceinline__ float bf2f_hi(unsigned int w) {
  return __uint_as_float(w & 0xFFFF0000u);
}
__device__ __forceinline__ unsigned short f2bf(float f) {
  unsigned int b = __float_as_uint(f);
  return (unsigned short)((b + 0x7FFFu + ((b >> 16) & 1u)) >> 16);
}

// Uniform front kernel: EVERY block does proj1 for 196 nodes (~1 us), then
// one scatter tile. 512 identical blocks = exactly 2 per CU -> balanced
// critical path (the R13/14 split-grid gave some CUs 3 scatter blocks).
__global__ __launch_bounds__(512) void k_front(
    const int* __restrict__ ei, const float* __restrict__ x,
    const float* __restrict__ Wl1, const float* __restrict__ Wr1,
    const float* __restrict__ b1, int* __restrict__ gcur,
    int* __restrict__ recs, unsigned short* __restrict__ p1h,
    float* __restrict__ q1b) {
  __shared__ int smem[11679];  // 46.7 KB
  const int t = threadIdx.x;

  // ---------------- phase 1: proj1 for nodes [blk*196, +196) --------------
  {
    float* sWl = (float*)smem;          // 512
    float* sWr = (float*)smem + 512;    // 512
    float* sb  = (float*)smem + 1024;   // 16
    sWl[t] = Wl1[t];
    sWr[t] = Wr1[t];
    if (t < 16) sb[t] = b1[t];
    __syncthreads();

    const int n = blockIdx.x * PRJ_PER_BLOCK + t;
    if (t < PRJ_PER_BLOCK && n < N_NODES) {
      float xr[32];
      const float4* xp = (const float4*)(x + (size_t)n * 32);
#pragma unroll
      for (int j = 0; j < 8; ++j) {
        float4 v = xp[j];
        xr[4 * j + 0] = v.x;
        xr[4 * j + 1] = v.y;
        xr[4 * j + 2] = v.z;
        xr[4 * j + 3] = v.w;
      }
      float pv[16], qv[16];
#pragma unroll
      for (int hh = 0; hh < 16; ++hh) {
        float a = 0.f, b = 0.f;
#pragma unroll
        for (int i = 0; i < 32; ++i) {
          a = fmaf(xr[i], sWl[hh * 32 + i], a);
          b = fmaf(xr[i], sWr[hh * 32 + i], b);
        }
        pv[hh] = a;
        qv[hh] = b + sb[hh];
      }
      unsigned int w[8];
#pragma unroll
      for (int j = 0; j < 8; ++j)
        w[j] = (unsigned int)f2bf(pv[2 * j]) |
               ((unsigned int)f2bf(pv[2 * j + 1]) << 16);
      uint4* pp = (uint4*)(p1h + (size_t)n * 16);
      pp[0] = make_uint4(w[0], w[1], w[2], w[3]);
      pp[1] = make_uint4(w[4], w[5], w[6], w[7]);
      float4* qp = (float4*)(q1b + (size_t)n * 16);
#pragma unroll
      for (int j = 0; j < 4; ++j)
        qp[j] =
            make_float4(qv[4 * j], qv[4 * j + 1], qv[4 * j + 2], qv[4 * j + 3]);
    }
    __syncthreads();
  }

  // ---------------- phase 2: tile counting-sort scatter (rank trick) ------
  int* hist   = smem;          // [0,1024)   counts -> exclusive scan (bstart)
  int* delta  = smem + 1024;   // [1024,1792) abs_base - bstart per bucket
  int* seg    = smem + 1792;   // [1792,2304)
  int* stage  = smem + 2304;   // [2304,8554)
  unsigned short* bid = (unsigned short*)(smem + 8554);  // TILE u16
  for (int i = t; i < 1024; i += 512) hist[i] = 0;
  __syncthreads();

  const int tb = blockIdx.x * TILE;
  int rec[MAXIT], aux[MAXIT];  // aux = (bucket<<16) | rank
#pragma unroll
  for (int i = 0; i < MAXIT; ++i) {
    const int pos = t + i * 512;
    if (pos < TILE) {
      const int e = tb + pos;
      const int s = ei[e];
      const int d = ei[N_EDGES + e];
      const int k = (int)((unsigned)d / 131u);
      const int rank = atomicAdd(&hist[k], 1);
      rec[i] = ((d - k * 131) << 17) | s;
      aux[i] = (k << 16) | rank;
    } else {
      aux[i] = -1;
    }
  }
  __syncthreads();

  // exclusive scan of hist[1024] with 512 threads (2 elems/thread)
  const int s0 = hist[2 * t], s1 = hist[2 * t + 1];
  const int my = s0 + s1;
  seg[t] = my;
  __syncthreads();
#pragma unroll
  for (int o = 1; o < 512; o <<= 1) {
    const int a = (t >= o) ? seg[t - o] : 0;
    __syncthreads();
    seg[t] += a;
    __syncthreads();
  }
  const int ex = seg[t] - my;
  hist[2 * t] = ex;
  hist[2 * t + 1] = ex + s0;
  // global reservation; delta[k] = absolute_base - bstart[k]
  {
    const int b = 2 * t;
    if (b < NB && s0) delta[b] = b * RSZ + atomicAdd(&gcur[b * 16], s0) - ex;
    if (b + 1 < NB && s1)
      delta[b + 1] =
          (b + 1) * RSZ + atomicAdd(&gcur[(b + 1) * 16], s1) - (ex + s0);
  }
  __syncthreads();

  // atomic-free placement + per-pos bucket-id fill
#pragma unroll
  for (int i = 0; i < MAXIT; ++i) {
    if (aux[i] >= 0) {
      const int k = aux[i] >> 16;
      stage[hist[k] + (aux[i] & 0xFFFF)] = rec[i];
    }
  }
  for (int k2 = t; k2 < NB; k2 += 512) {
    const int st = hist[k2];
    const int en = hist[k2 + 1];
    for (int p = st; p < en; ++p) bid[p] = (unsigned short)k2;
  }
  __syncthreads();

  // write-out in position order (L2-merged lines)
  for (int pos = t; pos < TILE; pos += 512) {
    const int k = bid[pos];
    const int idx = delta[k] + pos;
    if ((unsigned)idx < (unsigned)(NB * RSZ)) recs[idx] = stage[pos];
  }
}

// FUSED per-bucket sort (rank trick) + layer-1 aggregation; 768 blocks =
// exactly 3/CU. Writes node-sorted src back to recs + global-indexed CSR.
__global__ __launch_bounds__(512) void k_sortagg1(
    const int* __restrict__ gcur, int* __restrict__ recs,
    const unsigned short* __restrict__ p1h, const float* __restrict__ q1b,
    const float* __restrict__ Wl2, const float* __restrict__ Wr2,
    float* __restrict__ p2, float* __restrict__ r2,
    float* __restrict__ deg_inv, int* __restrict__ node_off,
    int* __restrict__ node_cnt) {
  __shared__ int hist[132];
  __shared__ int nstart[132];
  __shared__ int ssort[RSZ];
  __shared__ float sWl[16], sWr[16];
  const int t = threadIdx.x;
  const int kb = blockIdx.x;
  const int b0 = kb * RSZ;
  const int gend = b0 + gcur[kb * 16];
  if (t < 132) hist[t] = 0;
  if (t < 16) {
    sWl[t] = Wl2[t];
    sWr[t] = Wr2[t];
  }
  __syncthreads();

  int rc[MAXB], ax[MAXB];  // ax = (local<<13) | rank
#pragma unroll
  for (int i = 0; i < MAXB; ++i) {
    const int r = b0 + t + i * 512;
    if (r < gend) {
      const int rec = recs[r];
      const int local = rec >> 17;
      const int rank = atomicAdd(&hist[local], 1);
      rc[i] = rec & 0x1FFFF;
      ax[i] = (local << 13) | rank;
    } else {
      ax[i] = -1;
    }
  }
  __syncthreads();

  // exclusive scan of hist[132] -> nstart
  {
    int v = (t < 132) ? hist[t] : 0;
    if (t < 132) nstart[t] = v;
    __syncthreads();
#pragma unroll
    for (int o = 1; o < 132; o <<= 1) {
      const int a = (t < 132 && t >= o) ? nstart[t - o] : 0;
      __syncthreads();
      if (t < 132) nstart[t] += a;
      __syncthreads();
    }
    if (t < 132) nstart[t] -= v;
  }
  __syncthreads();

  // atomic-free placement into LDS
#pragma unroll
  for (int i = 0; i < MAXB; ++i) {
    if (ax[i] >= 0) ssort[nstart[ax[i] >> 13] + (ax[i] & 0x1FFF)] = rc[i];
  }
  __syncthreads();

  // coalesced write-back + global-indexed CSR metadata
  const int T = gend - b0;
  for (int j2 = t; j2 < T; j2 += 512) recs[b0 + j2] = ssort[j2];
  if (t < BKN) {
    const int n2 = kb * BKN + t;
    node_off[n2] = b0 + nstart[t];
    node_cnt[n2] = hist[t];
  }

  // aggregation: 4 lanes/node; quad = (edge-parity<<1)|channel-half
  const int quad = t & 3;
  const int half = quad & 1;
  const int epar = quad >> 1;
  const unsigned short* pb = p1h + half * 8;
#pragma unroll
  for (int p = 0; p < 2; ++p) {
    const int local = p * 128 + (t >> 2);
    if (local >= BKN) continue;  // quad-uniform branch (all 4 lanes agree)
    const int n = kb * BKN + local;
    if (n >= N_NODES) continue;
    const int st = nstart[local];
    const int k = hist[local];

    float acc[8];
#pragma unroll
    for (int i = 0; i < 8; ++i) acc[i] = 0.f;
    int j = epar;
    for (; j + 6 < k; j += 8) {
      const int s0 = ssort[st + j], s1 = ssort[st + j + 2],
                s2 = ssort[st + j + 4], s3 = ssort[st + j + 6];
      const uint4 w0 = *(const uint4*)(pb + (size_t)s0 * 16);
      const uint4 w1 = *(const uint4*)(pb + (size_t)s1 * 16);
      const uint4 w2 = *(const uint4*)(pb + (size_t)s2 * 16);
      const uint4 w3 = *(const uint4*)(pb + (size_t)s3 * 16);
      acc[0] +=
          (bf2f_lo(w0.x) + bf2f_lo(w1.x)) + (bf2f_lo(w2.x) + bf2f_lo(w3.x));
      acc[1] +=
          (bf2f_hi(w0.x) + bf2f_hi(w1.x)) + (bf2f_hi(w2.x) + bf2f_hi(w3.x));
      acc[2] +=
          (bf2f_lo(w0.y) + bf2f_lo(w1.y)) + (bf2f_lo(w2.y) + bf2f_lo(w3.y));
      acc[3] +=
          (bf2f_hi(w0.y) + bf2f_hi(w1.y)) + (bf2f_hi(w2.y) + bf2f_hi(w3.y));
      acc[4] +=
          (bf2f_lo(w0.z) + bf2f_lo(w1.z)) + (bf2f_lo(w2.z) + bf2f_lo(w3.z));
      acc[5] +=
          (bf2f_hi(w0.z) + bf2f_hi(w1.z)) + (bf2f_hi(w2.z) + bf2f_hi(w3.z));
      acc[6] +=
          (bf2f_lo(w0.w) + bf2f_lo(w1.w)) + (bf2f_lo(w2.w) + bf2f_lo(w3.w));
      acc[7] +=
          (bf2f_hi(w0.w) + bf2f_hi(w1.w)) + (bf2f_hi(w2.w) + bf2f_hi(w3.w));
    }
    for (; j < k; j += 2) {
      const uint4 w = *(const uint4*)(pb + (size_t)ssort[st + j] * 16);
      acc[0] += bf2f_lo(w.x);
      acc[1] += bf2f_hi(w.x);
      acc[2] += bf2f_lo(w.y);
      acc[3] += bf2f_hi(w.y);
      acc[4] += bf2f_lo(w.z);
      acc[5] += bf2f_hi(w.z);
      acc[6] += bf2f_lo(w.w);
      acc[7] += bf2f_hi(w.w);
    }
#pragma unroll
    for (int i = 0; i < 8; ++i) acc[i] += __shfl_xor(acc[i], 2);

    const float di = 1.f / fmaxf((float)k, 1.f);
    const float4* qp = (const float4*)(q1b + (size_t)n * 16 + half * 8);
    const float4 qa = qp[0], qb = qp[1];
    float h[8];
    h[0] = fmaxf(fmaf(acc[0], di, qa.x), 0.f);
    h[1] = fmaxf(fmaf(acc[1], di, qa.y), 0.f);
    h[2] = fmaxf(fmaf(acc[2], di, qa.z), 0.f);
    h[3] = fmaxf(fmaf(acc[3], di, qa.w), 0.f);
    h[4] = fmaxf(fmaf(acc[4], di, qb.x), 0.f);
    h[5] = fmaxf(fmaf(acc[5], di, qb.y), 0.f);
    h[6] = fmaxf(fmaf(acc[6], di, qb.z), 0.f);
    h[7] = fmaxf(fmaf(acc[7], di, qb.w), 0.f);
    float pa = 0.f, pbv = 0.f;
#pragma unroll
    for (int i = 0; i < 8; ++i) {
      pa = fmaf(h[i], sWl[half * 8 + i], pa);
      pbv = fmaf(h[i], sWr[half * 8 + i], pbv);
    }
    pa += __shfl_xor(pa, 1);
    pbv += __shfl_xor(pbv, 1);
    if (quad == 0) {
      p2[n] = pa;
      r2[n] = pbv;
      deg_inv[n] = di;
    }
  }
}

// layer-2 aggregation + output epilogue: node-sorted recs, 4 lanes/node,
// REGISTER accumulation; CSR is global-node-indexed.
__global__ __launch_bounds__(512) void k_agg2out(
    const int* __restrict__ node_off, const int* __restrict__ node_cnt,
    const int* __restrict__ recs, const float* __restrict__ p2,
    const float* __restrict__ r2, const float* __restrict__ deg_inv,
    const float* __restrict__ b2, float* __restrict__ out) {
  const int t = threadIdx.x;
  const int n = blockIdx.x * 128 + (t >> 2);
  const int c = t & 3;
  if (n >= N_NODES) return;
  const int k0 = node_off[n];
  const int k = node_cnt[n];
  const int* sl = recs + k0;

  float u = 0.f;
  int j = c;
  for (; j + 4 < k; j += 8) u += p2[sl[j]] + p2[sl[j + 4]];
  for (; j < k; j += 4) u += p2[sl[j]];
  u += __shfl_xor(u, 1);
  u += __shfl_xor(u, 2);
  if (c == 0) out[n] = fmaf(u, deg_inv[n], r2[n] + b2[0]);
}

extern "C" void kernel_launch(void* const* d_in, const int* in_sizes, int n_in,
                              void* d_out, int out_size, void* d_ws,
                              size_t ws_size, hipStream_t stream) {
  const float* x   = (const float*)d_in[0];
  const int*   ei  = (const int*)d_in[1];
  const float* Wl1 = (const float*)d_in[2];
  const float* Wr1 = (const float*)d_in[3];
  const float* b1  = (const float*)d_in[4];
  const float* Wl2 = (const float*)d_in[5];
  const float* Wr2 = (const float*)d_in[6];
  const float* b2  = (const float*)d_in[7];
  float* out = (float*)d_out;

  const size_t N = N_NODES;
  int* wi = (int*)d_ws;
  int* gcur     = wi;                                  // NB*16
  int* node_off = wi + NB * 16;                        // 100608
  int* node_cnt = node_off + 100608;                   // 100608
  int* recs     = node_cnt + 100608;                   // NB*RSZ
  unsigned short* p1h = (unsigned short*)(recs + (size_t)NB * RSZ);
  float* q1b     = (float*)(p1h + 16 * N);   // 16N ushorts = 8N words
  float* p2      = q1b + 16 * N;
  float* r2      = p2 + N;
  float* deg_inv = r2 + N;

  hipMemsetAsync(gcur, 0, NB * 16 * sizeof(int), stream);
  k_front<<<NTILES, 512, 0, stream>>>(ei, x, Wl1, Wr1, b1, gcur, recs, p1h,
                                      q1b);
  k_sortagg1<<<NB, 512, 0, stream>>>(gcur, recs, p1h, q1b, Wl2, Wr2, p2, r2,
                                     deg_inv, node_off, node_cnt);
  k_agg2out<<<(N_NODES + 127) / 128, 512, 0, stream>>>(
      node_off, node_cnt, recs, p2, r2, deg_inv, b2, out);
}

// Round 17
// 176.740 us; speedup vs baseline: 1.0463x; 1.0463x over previous
//
#include <hip/hip_runtime.h>

#define N_NODES 100000
#define N_EDGES 3200000
#define NB 768                         // buckets: exactly 3 sortagg blocks/CU
#define BKN 131                        // nodes per bucket (768*131=100608)
#define RSZ 5120                       // record window (mean 4167, +14 sigma)
#define TILE 6250
#define NTILES 512                     // 512*6250 == 3.2M exactly; 2 blocks/CU
#define MAXIT 13                       // ceil(TILE/512)
#define MAXB 10                        // ceil(RSZ/512)

// ---------------------------------------------------------------------------
// Workspace layout (4-byte elements):
//   gcur      NB*16 ints (relative cursor/bucket, one per 64B line; memset 0)
//   node_off  100608     (absolute start of node's run in recs)
//   node_cnt  100608     (in-degree per node)
//   recs      NB*RSZ     (pass A: (local_dst<<17)|src bucket-grouped;
//                         pass B: sortagg1 overwrites with node-sorted src)
//   p1h   16N ushorts = bf16(x @ Wl1^T)   (3.2 MB, L2-resident)
//   q1b   16N floats  = x @ Wr1^T + b1
//   p2 / r2 / deg_inv   N floats each
// ---------------------------------------------------------------------------

__device__ __forceinline__ float bf2f_lo(unsigned int w) {
  return __uint_as_float(w << 16);
}
__device__ __forceinline__ float bf2f_hi(unsigned int w) {
  return __uint_as_float(w & 0xFFFF0000u);
}
__device__ __forceinline__ unsigned short f2bf(float f) {
  unsigned int b = __float_as_uint(f);
  return (unsigned short)((b + 0x7FFFu + ((b >> 16) & 1u)) >> 16);
}

__global__ __launch_bounds__(512) void k_proj1(
    const float* __restrict__ x, const float* __restrict__ Wl1,
    const float* __restrict__ Wr1, const float* __restrict__ b1,
    unsigned short* __restrict__ p1h, float* __restrict__ q1b) {
  __shared__ float sWl[512];
  __shared__ float sWr[512];
  __shared__ float sb[16];
  const int t = threadIdx.x;
  sWl[t] = Wl1[t];
  sWr[t] = Wr1[t];
  if (t < 16) sb[t] = b1[t];
  __syncthreads();

  const int n = blockIdx.x * 512 + t;
  if (n >= N_NODES) return;

  float xr[32];
  const float4* xp = (const float4*)(x + (size_t)n * 32);
#pragma unroll
  for (int j = 0; j < 8; ++j) {
    float4 v = xp[j];
    xr[4 * j + 0] = v.x;
    xr[4 * j + 1] = v.y;
    xr[4 * j + 2] = v.z;
    xr[4 * j + 3] = v.w;
  }
  float pv[16], qv[16];
#pragma unroll
  for (int hh = 0; hh < 16; ++hh) {
    float a = 0.f, b = 0.f;
#pragma unroll
    for (int i = 0; i < 32; ++i) {
      a = fmaf(xr[i], sWl[hh * 32 + i], a);
      b = fmaf(xr[i], sWr[hh * 32 + i], b);
    }
    pv[hh] = a;
    qv[hh] = b + sb[hh];
  }
  unsigned int w[8];
#pragma unroll
  for (int j = 0; j < 8; ++j)
    w[j] = (unsigned int)f2bf(pv[2 * j]) |
           ((unsigned int)f2bf(pv[2 * j + 1]) << 16);
  uint4* pp = (uint4*)(p1h + (size_t)n * 16);
  pp[0] = make_uint4(w[0], w[1], w[2], w[3]);
  pp[1] = make_uint4(w[4], w[5], w[6], w[7]);
  float4* qp = (float4*)(q1b + (size_t)n * 16);
#pragma unroll
  for (int j = 0; j < 4; ++j)
    qp[j] = make_float4(qv[4 * j], qv[4 * j + 1], qv[4 * j + 2], qv[4 * j + 3]);
}

// Standalone tile counting-sort scatter: rank trick (1 LDS atomic/record) +
// bid/delta write-out (no dependent binary-search chain). 512x512 = 2/CU.
__global__ __launch_bounds__(512) void k_bscatter(const int* __restrict__ ei,
                                                  int* __restrict__ gcur,
                                                  int* __restrict__ recs) {
  __shared__ int hist[1024];   // counts -> exclusive scan (bstart); 0-padded
  __shared__ int delta[NB];    // absolute_base - bstart per bucket
  __shared__ int seg[512];
  __shared__ int stage[TILE];
  __shared__ unsigned short bid[TILE + 6];  // per-pos bucket id
  const int t = threadIdx.x;
  for (int i = t; i < 1024; i += 512) hist[i] = 0;
  __syncthreads();

  const int tb = blockIdx.x * TILE;
  int rec[MAXIT], aux[MAXIT];  // aux = (bucket<<16) | rank
#pragma unroll
  for (int i = 0; i < MAXIT; ++i) {
    const int pos = t + i * 512;
    if (pos < TILE) {
      const int e = tb + pos;
      const int s = ei[e];
      const int d = ei[N_EDGES + e];
      const int k = (int)((unsigned)d / (unsigned)BKN);
      const int rank = atomicAdd(&hist[k], 1);
      rec[i] = ((d - k * BKN) << 17) | s;
      aux[i] = (k << 16) | rank;
    } else {
      aux[i] = -1;
    }
  }
  __syncthreads();

  // exclusive scan of hist[1024] with 512 threads (2 elems/thread)
  const int s0 = hist[2 * t], s1 = hist[2 * t + 1];
  const int my = s0 + s1;
  seg[t] = my;
  __syncthreads();
#pragma unroll
  for (int o = 1; o < 512; o <<= 1) {
    const int a = (t >= o) ? seg[t - o] : 0;
    __syncthreads();
    seg[t] += a;
    __syncthreads();
  }
  const int ex = seg[t] - my;
  hist[2 * t] = ex;
  hist[2 * t + 1] = ex + s0;
  // global reservation; delta[k] = absolute_base - bstart[k]
  {
    const int b = 2 * t;
    if (b < NB && s0) delta[b] = b * RSZ + atomicAdd(&gcur[b * 16], s0) - ex;
    if (b + 1 < NB && s1)
      delta[b + 1] =
          (b + 1) * RSZ + atomicAdd(&gcur[(b + 1) * 16], s1) - (ex + s0);
  }
  __syncthreads();

  // atomic-free placement + per-pos bucket-id fill
#pragma unroll
  for (int i = 0; i < MAXIT; ++i) {
    if (aux[i] >= 0) stage[hist[aux[i] >> 16] + (aux[i] & 0xFFFF)] = rec[i];
  }
  for (int k2 = t; k2 < NB; k2 += 512) {
    const int st = hist[k2];
    const int en = hist[k2 + 1];  // hist[NB]==TILE from zero padding
    for (int p = st; p < en; ++p) bid[p] = (unsigned short)k2;
  }
  __syncthreads();

  // write-out in position order (L2-merged lines): 2 independent LDS reads
  for (int pos = t; pos < TILE; pos += 512) {
    const int idx = delta[bid[pos]] + pos;
    if ((unsigned)idx < (unsigned)(NB * RSZ)) recs[idx] = stage[pos];
  }
}

// FUSED per-bucket sort (rank trick) + layer-1 aggregation; 768 blocks =
// exactly 3/CU. Writes node-sorted src back to recs + global-indexed CSR.
__global__ __launch_bounds__(512) void k_sortagg1(
    const int* __restrict__ gcur, int* __restrict__ recs,
    const unsigned short* __restrict__ p1h, const float* __restrict__ q1b,
    const float* __restrict__ Wl2, const float* __restrict__ Wr2,
    float* __restrict__ p2, float* __restrict__ r2,
    float* __restrict__ deg_inv, int* __restrict__ node_off,
    int* __restrict__ node_cnt) {
  __shared__ int hist[132];
  __shared__ int nstart[132];
  __shared__ int ssort[RSZ];
  __shared__ float sWl[16], sWr[16];
  const int t = threadIdx.x;
  const int kb = blockIdx.x;
  const int b0 = kb * RSZ;
  const int gend = b0 + min(gcur[kb * 16], RSZ);
  if (t < 132) hist[t] = 0;
  if (t < 16) {
    sWl[t] = Wl2[t];
    sWr[t] = Wr2[t];
  }
  __syncthreads();

  int rc[MAXB], ax[MAXB];  // ax = (local<<13) | rank
#pragma unroll
  for (int i = 0; i < MAXB; ++i) {
    const int r = b0 + t + i * 512;
    if (r < gend) {
      const int rec = recs[r];
      const int local = rec >> 17;
      const int rank = atomicAdd(&hist[local], 1);
      rc[i] = rec & 0x1FFFF;
      ax[i] = (local << 13) | rank;
    } else {
      ax[i] = -1;
    }
  }
  __syncthreads();

  // exclusive scan of hist[132] -> nstart
  {
    int v = (t < 132) ? hist[t] : 0;
    if (t < 132) nstart[t] = v;
    __syncthreads();
#pragma unroll
    for (int o = 1; o < 132; o <<= 1) {
      const int a = (t < 132 && t >= o) ? nstart[t - o] : 0;
      __syncthreads();
      if (t < 132) nstart[t] += a;
      __syncthreads();
    }
    if (t < 132) nstart[t] -= v;
  }
  __syncthreads();

  // atomic-free placement into LDS
#pragma unroll
  for (int i = 0; i < MAXB; ++i) {
    if (ax[i] >= 0) ssort[nstart[ax[i] >> 13] + (ax[i] & 0x1FFF)] = rc[i];
  }
  __syncthreads();

  // coalesced write-back + global-indexed CSR metadata
  const int T = gend - b0;
  for (int j2 = t; j2 < T; j2 += 512) recs[b0 + j2] = ssort[j2];
  if (t < BKN) {
    const int n2 = kb * BKN + t;
    node_off[n2] = b0 + nstart[t];
    node_cnt[n2] = hist[t];
  }

  // aggregation: 4 lanes/node; quad = (edge-parity<<1)|channel-half
  const int quad = t & 3;
  const int half = quad & 1;
  const int epar = quad >> 1;
  const unsigned short* pb = p1h + half * 8;
#pragma unroll
  for (int p = 0; p < 2; ++p) {
    const int local = p * 128 + (t >> 2);
    if (local >= BKN) continue;  // quad-uniform branch
    const int n = kb * BKN + local;
    if (n >= N_NODES) continue;
    const int st = nstart[local];
    const int k = hist[local];

    float acc[8];
#pragma unroll
    for (int i = 0; i < 8; ++i) acc[i] = 0.f;
    int j = epar;
    for (; j + 6 < k; j += 8) {
      const int s0 = ssort[st + j], s1 = ssort[st + j + 2],
                s2 = ssort[st + j + 4], s3 = ssort[st + j + 6];
      const uint4 w0 = *(const uint4*)(pb + (size_t)s0 * 16);
      const uint4 w1 = *(const uint4*)(pb + (size_t)s1 * 16);
      const uint4 w2 = *(const uint4*)(pb + (size_t)s2 * 16);
      const uint4 w3 = *(const uint4*)(pb + (size_t)s3 * 16);
      acc[0] +=
          (bf2f_lo(w0.x) + bf2f_lo(w1.x)) + (bf2f_lo(w2.x) + bf2f_lo(w3.x));
      acc[1] +=
          (bf2f_hi(w0.x) + bf2f_hi(w1.x)) + (bf2f_hi(w2.x) + bf2f_hi(w3.x));
      acc[2] +=
          (bf2f_lo(w0.y) + bf2f_lo(w1.y)) + (bf2f_lo(w2.y) + bf2f_lo(w3.y));
      acc[3] +=
          (bf2f_hi(w0.y) + bf2f_hi(w1.y)) + (bf2f_hi(w2.y) + bf2f_hi(w3.y));
      acc[4] +=
          (bf2f_lo(w0.z) + bf2f_lo(w1.z)) + (bf2f_lo(w2.z) + bf2f_lo(w3.z));
      acc[5] +=
          (bf2f_hi(w0.z) + bf2f_hi(w1.z)) + (bf2f_hi(w2.z) + bf2f_hi(w3.z));
      acc[6] +=
          (bf2f_lo(w0.w) + bf2f_lo(w1.w)) + (bf2f_lo(w2.w) + bf2f_lo(w3.w));
      acc[7] +=
          (bf2f_hi(w0.w) + bf2f_hi(w1.w)) + (bf2f_hi(w2.w) + bf2f_hi(w3.w));
    }
    for (; j < k; j += 2) {
      const uint4 w = *(const uint4*)(pb + (size_t)ssort[st + j] * 16);
      acc[0] += bf2f_lo(w.x);
      acc[1] += bf2f_hi(w.x);
      acc[2] += bf2f_lo(w.y);
      acc[3] += bf2f_hi(w.y);
      acc[4] += bf2f_lo(w.z);
      acc[5] += bf2f_hi(w.z);
      acc[6] += bf2f_lo(w.w);
      acc[7] += bf2f_hi(w.w);
    }
#pragma unroll
    for (int i = 0; i < 8; ++i) acc[i] += __shfl_xor(acc[i], 2);

    const float di = 1.f / fmaxf((float)k, 1.f);
    const float4* qp = (const float4*)(q1b + (size_t)n * 16 + half * 8);
    const float4 qa = qp[0], qb = qp[1];
    float h[8];
    h[0] = fmaxf(fmaf(acc[0], di, qa.x), 0.f);
    h[1] = fmaxf(fmaf(acc[1], di, qa.y), 0.f);
    h[2] = fmaxf(fmaf(acc[2], di, qa.z), 0.f);
    h[3] = fmaxf(fmaf(acc[3], di, qa.w), 0.f);
    h[4] = fmaxf(fmaf(acc[4], di, qb.x), 0.f);
    h[5] = fmaxf(fmaf(acc[5], di, qb.y), 0.f);
    h[6] = fmaxf(fmaf(acc[6], di, qb.z), 0.f);
    h[7] = fmaxf(fmaf(acc[7], di, qb.w), 0.f);
    float pa = 0.f, pbv = 0.f;
#pragma unroll
    for (int i = 0; i < 8; ++i) {
      pa = fmaf(h[i], sWl[half * 8 + i], pa);
      pbv = fmaf(h[i], sWr[half * 8 + i], pbv);
    }
    pa += __shfl_xor(pa, 1);
    pbv += __shfl_xor(pbv, 1);
    if (quad == 0) {
      p2[n] = pa;
      r2[n] = pbv;
      deg_inv[n] = di;
    }
  }
}

// layer-2 aggregation + output epilogue: node-sorted recs, 4 lanes/node,
// REGISTER accumulation; CSR is global-node-indexed.
__global__ __launch_bounds__(512) void k_agg2out(
    const int* __restrict__ node_off, const int* __restrict__ node_cnt,
    const int* __restrict__ recs, const float* __restrict__ p2,
    const float* __restrict__ r2, const float* __restrict__ deg_inv,
    const float* __restrict__ b2, float* __restrict__ out) {
  const int t = threadIdx.x;
  const int n = blockIdx.x * 128 + (t >> 2);
  const int c = t & 3;
  if (n >= N_NODES) return;
  const int k0 = node_off[n];
  const int k = node_cnt[n];
  const int* sl = recs + k0;

  float u = 0.f;
  int j = c;
  for (; j + 4 < k; j += 8) u += p2[sl[j]] + p2[sl[j + 4]];
  for (; j < k; j += 4) u += p2[sl[j]];
  u += __shfl_xor(u, 1);
  u += __shfl_xor(u, 2);
  if (c == 0) out[n] = fmaf(u, deg_inv[n], r2[n] + b2[0]);
}

extern "C" void kernel_launch(void* const* d_in, const int* in_sizes, int n_in,
                              void* d_out, int out_size, void* d_ws,
                              size_t ws_size, hipStream_t stream) {
  const float* x   = (const float*)d_in[0];
  const int*   ei  = (const int*)d_in[1];
  const float* Wl1 = (const float*)d_in[2];
  const float* Wr1 = (const float*)d_in[3];
  const float* b1  = (const float*)d_in[4];
  const float* Wl2 = (const float*)d_in[5];
  const float* Wr2 = (const float*)d_in[6];
  const float* b2  = (const float*)d_in[7];
  float* out = (float*)d_out;

  const size_t N = N_NODES;
  int* wi = (int*)d_ws;
  int* gcur     = wi;                                  // NB*16
  int* node_off = wi + NB * 16;                        // 100608
  int* node_cnt = node_off + 100608;                   // 100608
  int* recs     = node_cnt + 100608;                   // NB*RSZ
  unsigned short* p1h = (unsigned short*)(recs + (size_t)NB * RSZ);
  float* q1b     = (float*)(p1h + 16 * N);   // 16N ushorts = 8N words
  float* p2      = q1b + 16 * N;
  float* r2      = p2 + N;
  float* deg_inv = r2 + N;

  hipMemsetAsync(gcur, 0, NB * 16 * sizeof(int), stream);
  k_proj1<<<(N_NODES + 511) / 512, 512, 0, stream>>>(x, Wl1, Wr1, b1, p1h,
                                                     q1b);
  k_bscatter<<<NTILES, 512, 0, stream>>>(ei, gcur, recs);
  k_sortagg1<<<NB, 512, 0, stream>>>(gcur, recs, p1h, q1b, Wl2, Wr2, p2, r2,
                                     deg_inv, node_off, node_cnt);
  k_agg2out<<<(N_NODES + 127) / 128, 512, 0, stream>>>(
      node_off, node_cnt, recs, p2, r2, deg_inv, b2, out);
}

// Round 18
// 174.090 us; speedup vs baseline: 1.0623x; 1.0152x over previous
//
#include <hip/hip_runtime.h>

#define N_NODES 100000
#define N_EDGES 3200000
#define NB 768                         // buckets: exactly 3 sortagg blocks/CU
#define BKN 131                        // nodes per bucket (768*131=100608)
#define RSZ 5120                       // record window (mean 4167, +14 sigma)
#define TILE 6250
#define NTILES 512                     // 512*6250 == 3.2M exactly; 2 blocks/CU
#define MAXIT 13                       // ceil(TILE/512)
#define MAXB 10                        // ceil(RSZ/512)

// ---------------------------------------------------------------------------
// Workspace layout (4-byte elements):
//   gcur      NB*16 ints (relative cursor/bucket, 1/64B line; init in k_proj1)
//   node_off  100608     (absolute start of node's run in recs)
//   node_cnt  100608     (in-degree per node)
//   recs      NB*RSZ     (pass A: (local_dst<<17)|src bucket-grouped;
//                         pass B: sortagg1 overwrites with node-sorted src)
//   p1h   16N ushorts = bf16(x @ Wl1^T)   (3.2 MB, L2-resident)
//   q1b   16N floats  = x @ Wr1^T + b1
//   p2 / r2 / deg_inv   N floats each
// ---------------------------------------------------------------------------

__device__ __forceinline__ float bf2f_lo(unsigned int w) {
  return __uint_as_float(w << 16);
}
__device__ __forceinline__ float bf2f_hi(unsigned int w) {
  return __uint_as_float(w & 0xFFFF0000u);
}
__device__ __forceinline__ unsigned short f2bf(float f) {
  unsigned int b = __float_as_uint(f);
  return (unsigned short)((b + 0x7FFFu + ((b >> 16) & 1u)) >> 16);
}

// proj1 + gcur zero-init (folds away the memset dispatch; stream order
// guarantees gcur is ready before k_bscatter launches).
__global__ __launch_bounds__(512) void k_proj1(
    const float* __restrict__ x, const float* __restrict__ Wl1,
    const float* __restrict__ Wr1, const float* __restrict__ b1,
    unsigned short* __restrict__ p1h, float* __restrict__ q1b,
    int* __restrict__ gcur) {
  __shared__ float sWl[512];
  __shared__ float sWr[512];
  __shared__ float sb[16];
  const int t = threadIdx.x;
  if (t < 64) {
    const int gi = blockIdx.x * 64 + t;
    if (gi < NB * 16) gcur[gi] = 0;
  }
  sWl[t] = Wl1[t];
  sWr[t] = Wr1[t];
  if (t < 16) sb[t] = b1[t];
  __syncthreads();

  const int n = blockIdx.x * 512 + t;
  if (n >= N_NODES) return;

  float xr[32];
  const float4* xp = (const float4*)(x + (size_t)n * 32);
#pragma unroll
  for (int j = 0; j < 8; ++j) {
    float4 v = xp[j];
    xr[4 * j + 0] = v.x;
    xr[4 * j + 1] = v.y;
    xr[4 * j + 2] = v.z;
    xr[4 * j + 3] = v.w;
  }
  float pv[16], qv[16];
#pragma unroll
  for (int hh = 0; hh < 16; ++hh) {
    float a = 0.f, b = 0.f;
#pragma unroll
    for (int i = 0; i < 32; ++i) {
      a = fmaf(xr[i], sWl[hh * 32 + i], a);
      b = fmaf(xr[i], sWr[hh * 32 + i], b);
    }
    pv[hh] = a;
    qv[hh] = b + sb[hh];
  }
  unsigned int w[8];
#pragma unroll
  for (int j = 0; j < 8; ++j)
    w[j] = (unsigned int)f2bf(pv[2 * j]) |
           ((unsigned int)f2bf(pv[2 * j + 1]) << 16);
  uint4* pp = (uint4*)(p1h + (size_t)n * 16);
  pp[0] = make_uint4(w[0], w[1], w[2], w[3]);
  pp[1] = make_uint4(w[4], w[5], w[6], w[7]);
  float4* qp = (float4*)(q1b + (size_t)n * 16);
#pragma unroll
  for (int j = 0; j < 4; ++j)
    qp[j] = make_float4(qv[4 * j], qv[4 * j + 1], qv[4 * j + 2], qv[4 * j + 3]);
}

// Standalone tile counting-sort scatter: rank trick (1 LDS atomic/record) +
// bid/delta write-out (no dependent binary-search chain). 512x512 = 2/CU.
__global__ __launch_bounds__(512) void k_bscatter(const int* __restrict__ ei,
                                                  int* __restrict__ gcur,
                                                  int* __restrict__ recs) {
  __shared__ int hist[1024];   // counts -> exclusive scan (bstart); 0-padded
  __shared__ int delta[NB];    // absolute_base - bstart per bucket
  __shared__ int seg[512];
  __shared__ int stage[TILE];
  __shared__ unsigned short bid[TILE + 6];  // per-pos bucket id
  const int t = threadIdx.x;
  for (int i = t; i < 1024; i += 512) hist[i] = 0;
  __syncthreads();

  const int tb = blockIdx.x * TILE;
  int rec[MAXIT], aux[MAXIT];  // aux = (bucket<<16) | rank
#pragma unroll
  for (int i = 0; i < MAXIT; ++i) {
    const int pos = t + i * 512;
    if (pos < TILE) {
      const int e = tb + pos;
      const int s = ei[e];
      const int d = ei[N_EDGES + e];
      const int k = (int)((unsigned)d / (unsigned)BKN);
      const int rank = atomicAdd(&hist[k], 1);
      rec[i] = ((d - k * BKN) << 17) | s;
      aux[i] = (k << 16) | rank;
    } else {
      aux[i] = -1;
    }
  }
  __syncthreads();

  // exclusive scan of hist[1024] with 512 threads (2 elems/thread)
  const int s0 = hist[2 * t], s1 = hist[2 * t + 1];
  const int my = s0 + s1;
  seg[t] = my;
  __syncthreads();
#pragma unroll
  for (int o = 1; o < 512; o <<= 1) {
    const int a = (t >= o) ? seg[t - o] : 0;
    __syncthreads();
    seg[t] += a;
    __syncthreads();
  }
  const int ex = seg[t] - my;
  hist[2 * t] = ex;
  hist[2 * t + 1] = ex + s0;
  // global reservation; delta[k] = absolute_base - bstart[k]
  {
    const int b = 2 * t;
    if (b < NB && s0) delta[b] = b * RSZ + atomicAdd(&gcur[b * 16], s0) - ex;
    if (b + 1 < NB && s1)
      delta[b + 1] =
          (b + 1) * RSZ + atomicAdd(&gcur[(b + 1) * 16], s1) - (ex + s0);
  }
  __syncthreads();

  // atomic-free placement + per-pos bucket-id fill
#pragma unroll
  for (int i = 0; i < MAXIT; ++i) {
    if (aux[i] >= 0) stage[hist[aux[i] >> 16] + (aux[i] & 0xFFFF)] = rec[i];
  }
  for (int k2 = t; k2 < NB; k2 += 512) {
    const int st = hist[k2];
    const int en = hist[k2 + 1];  // hist[NB]==TILE from zero padding
    for (int p = st; p < en; ++p) bid[p] = (unsigned short)k2;
  }
  __syncthreads();

  // write-out in position order (L2-merged lines): 2 independent LDS reads
  for (int pos = t; pos < TILE; pos += 512) {
    const int idx = delta[bid[pos]] + pos;
    if ((unsigned)idx < (unsigned)(NB * RSZ)) recs[idx] = stage[pos];
  }
}

// FUSED per-bucket sort (rank trick) + layer-1 aggregation; 768 blocks =
// exactly 3/CU. Writes node-sorted src back to recs + global-indexed CSR.
__global__ __launch_bounds__(512) void k_sortagg1(
    const int* __restrict__ gcur, int* __restrict__ recs,
    const unsigned short* __restrict__ p1h, const float* __restrict__ q1b,
    const float* __restrict__ Wl2, const float* __restrict__ Wr2,
    float* __restrict__ p2, float* __restrict__ r2,
    float* __restrict__ deg_inv, int* __restrict__ node_off,
    int* __restrict__ node_cnt) {
  __shared__ int hist[132];
  __shared__ int nstart[132];
  __shared__ int ssort[RSZ];
  __shared__ float sWl[16], sWr[16];
  const int t = threadIdx.x;
  const int kb = blockIdx.x;
  const int b0 = kb * RSZ;
  const int gend = b0 + min(gcur[kb * 16], RSZ);
  if (t < 132) hist[t] = 0;
  if (t < 16) {
    sWl[t] = Wl2[t];
    sWr[t] = Wr2[t];
  }
  __syncthreads();

  int rc[MAXB], ax[MAXB];  // ax = (local<<13) | rank
#pragma unroll
  for (int i = 0; i < MAXB; ++i) {
    const int r = b0 + t + i * 512;
    if (r < gend) {
      const int rec = recs[r];
      const int local = rec >> 17;
      const int rank = atomicAdd(&hist[local], 1);
      rc[i] = rec & 0x1FFFF;
      ax[i] = (local << 13) | rank;
    } else {
      ax[i] = -1;
    }
  }
  __syncthreads();

  // exclusive scan of hist[132] -> nstart
  {
    int v = (t < 132) ? hist[t] : 0;
    if (t < 132) nstart[t] = v;
    __syncthreads();
#pragma unroll
    for (int o = 1; o < 132; o <<= 1) {
      const int a = (t < 132 && t >= o) ? nstart[t - o] : 0;
      __syncthreads();
      if (t < 132) nstart[t] += a;
      __syncthreads();
    }
    if (t < 132) nstart[t] -= v;
  }
  __syncthreads();

  // atomic-free placement into LDS
#pragma unroll
  for (int i = 0; i < MAXB; ++i) {
    if (ax[i] >= 0) ssort[nstart[ax[i] >> 13] + (ax[i] & 0x1FFF)] = rc[i];
  }
  __syncthreads();

  // coalesced write-back + global-indexed CSR metadata
  const int T = gend - b0;
  for (int j2 = t; j2 < T; j2 += 512) recs[b0 + j2] = ssort[j2];
  if (t < BKN) {
    const int n2 = kb * BKN + t;
    node_off[n2] = b0 + nstart[t];
    node_cnt[n2] = hist[t];
  }

  // aggregation: 4 lanes/node; quad = (edge-parity<<1)|channel-half
  const int quad = t & 3;
  const int half = quad & 1;
  const int epar = quad >> 1;
  const unsigned short* pb = p1h + half * 8;
#pragma unroll
  for (int p = 0; p < 2; ++p) {
    const int local = p * 128 + (t >> 2);
    if (local >= BKN) continue;  // quad-uniform branch
    const int n = kb * BKN + local;
    if (n >= N_NODES) continue;
    const int st = nstart[local];
    const int k = hist[local];

    float acc[8];
#pragma unroll
    for (int i = 0; i < 8; ++i) acc[i] = 0.f;
    int j = epar;
    for (; j + 6 < k; j += 8) {
      const int s0 = ssort[st + j], s1 = ssort[st + j + 2],
                s2 = ssort[st + j + 4], s3 = ssort[st + j + 6];
      const uint4 w0 = *(const uint4*)(pb + (size_t)s0 * 16);
      const uint4 w1 = *(const uint4*)(pb + (size_t)s1 * 16);
      const uint4 w2 = *(const uint4*)(pb + (size_t)s2 * 16);
      const uint4 w3 = *(const uint4*)(pb + (size_t)s3 * 16);
      acc[0] +=
          (bf2f_lo(w0.x) + bf2f_lo(w1.x)) + (bf2f_lo(w2.x) + bf2f_lo(w3.x));
      acc[1] +=
          (bf2f_hi(w0.x) + bf2f_hi(w1.x)) + (bf2f_hi(w2.x) + bf2f_hi(w3.x));
      acc[2] +=
          (bf2f_lo(w0.y) + bf2f_lo(w1.y)) + (bf2f_lo(w2.y) + bf2f_lo(w3.y));
      acc[3] +=
          (bf2f_hi(w0.y) + bf2f_hi(w1.y)) + (bf2f_hi(w2.y) + bf2f_hi(w3.y));
      acc[4] +=
          (bf2f_lo(w0.z) + bf2f_lo(w1.z)) + (bf2f_lo(w2.z) + bf2f_lo(w3.z));
      acc[5] +=
          (bf2f_hi(w0.z) + bf2f_hi(w1.z)) + (bf2f_hi(w2.z) + bf2f_hi(w3.z));
      acc[6] +=
          (bf2f_lo(w0.w) + bf2f_lo(w1.w)) + (bf2f_lo(w2.w) + bf2f_lo(w3.w));
      acc[7] +=
          (bf2f_hi(w0.w) + bf2f_hi(w1.w)) + (bf2f_hi(w2.w) + bf2f_hi(w3.w));
    }
    for (; j < k; j += 2) {
      const uint4 w = *(const uint4*)(pb + (size_t)ssort[st + j] * 16);
      acc[0] += bf2f_lo(w.x);
      acc[1] += bf2f_hi(w.x);
      acc[2] += bf2f_lo(w.y);
      acc[3] += bf2f_hi(w.y);
      acc[4] += bf2f_lo(w.z);
      acc[5] += bf2f_hi(w.z);
      acc[6] += bf2f_lo(w.w);
      acc[7] += bf2f_hi(w.w);
    }
#pragma unroll
    for (int i = 0; i < 8; ++i) acc[i] += __shfl_xor(acc[i], 2);

    const float di = 1.f / fmaxf((float)k, 1.f);
    const float4* qp = (const float4*)(q1b + (size_t)n * 16 + half * 8);
    const float4 qa = qp[0], qb = qp[1];
    float h[8];
    h[0] = fmaxf(fmaf(acc[0], di, qa.x), 0.f);
    h[1] = fmaxf(fmaf(acc[1], di, qa.y), 0.f);
    h[2] = fmaxf(fmaf(acc[2], di, qa.z), 0.f);
    h[3] = fmaxf(fmaf(acc[3], di, qa.w), 0.f);
    h[4] = fmaxf(fmaf(acc[4], di, qb.x), 0.f);
    h[5] = fmaxf(fmaf(acc[5], di, qb.y), 0.f);
    h[6] = fmaxf(fmaf(acc[6], di, qb.z), 0.f);
    h[7] = fmaxf(fmaf(acc[7], di, qb.w), 0.f);
    float pa = 0.f, pbv = 0.f;
#pragma unroll
    for (int i = 0; i < 8; ++i) {
      pa = fmaf(h[i], sWl[half * 8 + i], pa);
      pbv = fmaf(h[i], sWr[half * 8 + i], pbv);
    }
    pa += __shfl_xor(pa, 1);
    pbv += __shfl_xor(pbv, 1);
    if (quad == 0) {
      p2[n] = pa;
      r2[n] = pbv;
      deg_inv[n] = di;
    }
  }
}

// layer-2 aggregation + output epilogue: node-sorted recs, 4 lanes/node,
// REGISTER accumulation with 4 gathers in flight.
__global__ __launch_bounds__(512) void k_agg2out(
    const int* __restrict__ node_off, const int* __restrict__ node_cnt,
    const int* __restrict__ recs, const float* __restrict__ p2,
    const float* __restrict__ r2, const float* __restrict__ deg_inv,
    const float* __restrict__ b2, float* __restrict__ out) {
  const int t = threadIdx.x;
  const int n = blockIdx.x * 128 + (t >> 2);
  const int c = t & 3;
  if (n >= N_NODES) return;
  const int k0 = node_off[n];
  const int k = node_cnt[n];
  const int* sl = recs + k0;

  float u = 0.f;
  int j = c;
  for (; j + 12 < k; j += 16) {
    const int sA = sl[j], sB = sl[j + 4], sC = sl[j + 8], sD = sl[j + 12];
    u += (p2[sA] + p2[sB]) + (p2[sC] + p2[sD]);
  }
  for (; j < k; j += 4) u += p2[sl[j]];
  u += __shfl_xor(u, 1);
  u += __shfl_xor(u, 2);
  if (c == 0) out[n] = fmaf(u, deg_inv[n], r2[n] + b2[0]);
}

extern "C" void kernel_launch(void* const* d_in, const int* in_sizes, int n_in,
                              void* d_out, int out_size, void* d_ws,
                              size_t ws_size, hipStream_t stream) {
  const float* x   = (const float*)d_in[0];
  const int*   ei  = (const int*)d_in[1];
  const float* Wl1 = (const float*)d_in[2];
  const float* Wr1 = (const float*)d_in[3];
  const float* b1  = (const float*)d_in[4];
  const float* Wl2 = (const float*)d_in[5];
  const float* Wr2 = (const float*)d_in[6];
  const float* b2  = (const float*)d_in[7];
  float* out = (float*)d_out;

  const size_t N = N_NODES;
  int* wi = (int*)d_ws;
  int* gcur     = wi;                                  // NB*16
  int* node_off = wi + NB * 16;                        // 100608
  int* node_cnt = node_off + 100608;                   // 100608
  int* recs     = node_cnt + 100608;                   // NB*RSZ
  unsigned short* p1h = (unsigned short*)(recs + (size_t)NB * RSZ);
  float* q1b     = (float*)(p1h + 16 * N);   // 16N ushorts = 8N words
  float* p2      = q1b + 16 * N;
  float* r2      = p2 + N;
  float* deg_inv = r2 + N;

  k_proj1<<<(N_NODES + 511) / 512, 512, 0, stream>>>(x, Wl1, Wr1, b1, p1h,
                                                     q1b, gcur);
  k_bscatter<<<NTILES, 512, 0, stream>>>(ei, gcur, recs);
  k_sortagg1<<<NB, 512, 0, stream>>>(gcur, recs, p1h, q1b, Wl2, Wr2, p2, r2,
                                     deg_inv, node_off, node_cnt);
  k_agg2out<<<(N_NODES + 127) / 128, 512, 0, stream>>>(
      node_off, node_cnt, recs, p2, r2, deg_inv, b2, out);
}

// Round 19
// 173.768 us; speedup vs baseline: 1.0642x; 1.0019x over previous
//
#include <hip/hip_runtime.h>

#define N_NODES 100000
#define N_EDGES 3200000
#define NB 768                         // buckets: exactly 3 blocks/CU
#define BKN 131                        // nodes per bucket (768*131=100608)
#define RSZ 5120                       // record window (mean 4167, +14 sigma)
#define TILE 6250
#define NTILES 512                     // 512*6250 == 3.2M exactly; 2 blocks/CU
#define MAXIT 13                       // ceil(TILE/512)
#define MAXB 10                        // ceil(RSZ/512)

// ---------------------------------------------------------------------------
// Workspace layout (4-byte elements):
//   gcur      NB*16 ints (relative cursor/bucket, 1/64B line; init in k_proj1)
//   node_off  100608     (absolute start of node's run in recs)
//   node_cnt  100608     (in-degree per node)
//   recs      NB*RSZ     (pass A: (local_dst<<17)|src bucket-grouped;
//                         pass B: sortagg1 overwrites with node-sorted src)
//   p1h   16N ushorts = bf16(x @ Wl1^T)   (3.2 MB, L2-resident)
//   q1b   16N floats  = x @ Wr1^T + b1
//   p2 / r2 / deg_inv   N floats each
// ---------------------------------------------------------------------------

__device__ __forceinline__ float bf2f_lo(unsigned int w) {
  return __uint_as_float(w << 16);
}
__device__ __forceinline__ float bf2f_hi(unsigned int w) {
  return __uint_as_float(w & 0xFFFF0000u);
}
__device__ __forceinline__ unsigned short f2bf(float f) {
  unsigned int b = __float_as_uint(f);
  return (unsigned short)((b + 0x7FFFu + ((b >> 16) & 1u)) >> 16);
}

// proj1 + gcur zero-init. 256-thread blocks x 391 -> all 256 CUs covered.
__global__ __launch_bounds__(256) void k_proj1(
    const float* __restrict__ x, const float* __restrict__ Wl1,
    const float* __restrict__ Wr1, const float* __restrict__ b1,
    unsigned short* __restrict__ p1h, float* __restrict__ q1b,
    int* __restrict__ gcur) {
  __shared__ float sWl[512];
  __shared__ float sWr[512];
  __shared__ float sb[16];
  const int t = threadIdx.x;
  if (t < 32) {
    const int gi = blockIdx.x * 32 + t;
    if (gi < NB * 16) gcur[gi] = 0;
  }
  for (int i = t; i < 512; i += 256) {
    sWl[i] = Wl1[i];
    sWr[i] = Wr1[i];
  }
  if (t < 16) sb[t] = b1[t];
  __syncthreads();

  const int n = blockIdx.x * 256 + t;
  if (n >= N_NODES) return;

  float xr[32];
  const float4* xp = (const float4*)(x + (size_t)n * 32);
#pragma unroll
  for (int j = 0; j < 8; ++j) {
    float4 v = xp[j];
    xr[4 * j + 0] = v.x;
    xr[4 * j + 1] = v.y;
    xr[4 * j + 2] = v.z;
    xr[4 * j + 3] = v.w;
  }
  float pv[16], qv[16];
#pragma unroll
  for (int hh = 0; hh < 16; ++hh) {
    float a = 0.f, b = 0.f;
#pragma unroll
    for (int i = 0; i < 32; ++i) {
      a = fmaf(xr[i], sWl[hh * 32 + i], a);
      b = fmaf(xr[i], sWr[hh * 32 + i], b);
    }
    pv[hh] = a;
    qv[hh] = b + sb[hh];
  }
  unsigned int w[8];
#pragma unroll
  for (int j = 0; j < 8; ++j)
    w[j] = (unsigned int)f2bf(pv[2 * j]) |
           ((unsigned int)f2bf(pv[2 * j + 1]) << 16);
  uint4* pp = (uint4*)(p1h + (size_t)n * 16);
  pp[0] = make_uint4(w[0], w[1], w[2], w[3]);
  pp[1] = make_uint4(w[4], w[5], w[6], w[7]);
  float4* qp = (float4*)(q1b + (size_t)n * 16);
#pragma unroll
  for (int j = 0; j < 4; ++j)
    qp[j] = make_float4(qv[4 * j], qv[4 * j + 1], qv[4 * j + 2], qv[4 * j + 3]);
}

// Standalone tile counting-sort scatter: rank trick (1 LDS atomic/record) +
// bid/delta write-out (no dependent binary-search chain). 512x512 = 2/CU.
__global__ __launch_bounds__(512) void k_bscatter(const int* __restrict__ ei,
                                                  int* __restrict__ gcur,
                                                  int* __restrict__ recs) {
  __shared__ int hist[1024];   // counts -> exclusive scan (bstart); 0-padded
  __shared__ int delta[NB];    // absolute_base - bstart per bucket
  __shared__ int seg[512];
  __shared__ int stage[TILE];
  __shared__ unsigned short bid[TILE + 6];  // per-pos bucket id
  const int t = threadIdx.x;
  for (int i = t; i < 1024; i += 512) hist[i] = 0;
  __syncthreads();

  const int tb = blockIdx.x * TILE;
  int rec[MAXIT], aux[MAXIT];  // aux = (bucket<<16) | rank
#pragma unroll
  for (int i = 0; i < MAXIT; ++i) {
    const int pos = t + i * 512;
    if (pos < TILE) {
      const int e = tb + pos;
      const int s = ei[e];
      const int d = ei[N_EDGES + e];
      const int k = (int)((unsigned)d / (unsigned)BKN);
      const int rank = atomicAdd(&hist[k], 1);
      rec[i] = ((d - k * BKN) << 17) | s;
      aux[i] = (k << 16) | rank;
    } else {
      aux[i] = -1;
    }
  }
  __syncthreads();

  // exclusive scan of hist[1024] with 512 threads (2 elems/thread)
  const int s0 = hist[2 * t], s1 = hist[2 * t + 1];
  const int my = s0 + s1;
  seg[t] = my;
  __syncthreads();
#pragma unroll
  for (int o = 1; o < 512; o <<= 1) {
    const int a = (t >= o) ? seg[t - o] : 0;
    __syncthreads();
    seg[t] += a;
    __syncthreads();
  }
  const int ex = seg[t] - my;
  hist[2 * t] = ex;
  hist[2 * t + 1] = ex + s0;
  // global reservation; delta[k] = absolute_base - bstart[k]
  {
    const int b = 2 * t;
    if (b < NB && s0) delta[b] = b * RSZ + atomicAdd(&gcur[b * 16], s0) - ex;
    if (b + 1 < NB && s1)
      delta[b + 1] =
          (b + 1) * RSZ + atomicAdd(&gcur[(b + 1) * 16], s1) - (ex + s0);
  }
  __syncthreads();

  // atomic-free placement + per-pos bucket-id fill
#pragma unroll
  for (int i = 0; i < MAXIT; ++i) {
    if (aux[i] >= 0) stage[hist[aux[i] >> 16] + (aux[i] & 0xFFFF)] = rec[i];
  }
  for (int k2 = t; k2 < NB; k2 += 512) {
    const int st = hist[k2];
    const int en = hist[k2 + 1];  // hist[NB]==TILE from zero padding
    for (int p = st; p < en; ++p) bid[p] = (unsigned short)k2;
  }
  __syncthreads();

  // write-out in position order (L2-merged lines): 2 independent LDS reads
  for (int pos = t; pos < TILE; pos += 512) {
    const int idx = delta[bid[pos]] + pos;
    if ((unsigned)idx < (unsigned)(NB * RSZ)) recs[idx] = stage[pos];
  }
}

// FUSED per-bucket sort (rank trick) + layer-1 aggregation; 768 blocks =
// exactly 3/CU. Writes node-sorted src back to recs + global-indexed CSR.
__global__ __launch_bounds__(512) void k_sortagg1(
    const int* __restrict__ gcur, int* __restrict__ recs,
    const unsigned short* __restrict__ p1h, const float* __restrict__ q1b,
    const float* __restrict__ Wl2, const float* __restrict__ Wr2,
    float* __restrict__ p2, float* __restrict__ r2,
    float* __restrict__ deg_inv, int* __restrict__ node_off,
    int* __restrict__ node_cnt) {
  __shared__ int hist[132];
  __shared__ int nstart[132];
  __shared__ int ssort[RSZ];
  __shared__ float sWl[16], sWr[16];
  const int t = threadIdx.x;
  const int kb = blockIdx.x;
  const int b0 = kb * RSZ;
  const int gend = b0 + min(gcur[kb * 16], RSZ);
  if (t < 132) hist[t] = 0;
  if (t < 16) {
    sWl[t] = Wl2[t];
    sWr[t] = Wr2[t];
  }
  __syncthreads();

  int rc[MAXB], ax[MAXB];  // ax = (local<<13) | rank
#pragma unroll
  for (int i = 0; i < MAXB; ++i) {
    const int r = b0 + t + i * 512;
    if (r < gend) {
      const int rec = recs[r];
      const int local = rec >> 17;
      const int rank = atomicAdd(&hist[local], 1);
      rc[i] = rec & 0x1FFFF;
      ax[i] = (local << 13) | rank;
    } else {
      ax[i] = -1;
    }
  }
  __syncthreads();

  // exclusive scan of hist[132] -> nstart
  {
    int v = (t < 132) ? hist[t] : 0;
    if (t < 132) nstart[t] = v;
    __syncthreads();
#pragma unroll
    for (int o = 1; o < 132; o <<= 1) {
      const int a = (t < 132 && t >= o) ? nstart[t - o] : 0;
      __syncthreads();
      if (t < 132) nstart[t] += a;
      __syncthreads();
    }
    if (t < 132) nstart[t] -= v;
  }
  __syncthreads();

  // atomic-free placement into LDS
#pragma unroll
  for (int i = 0; i < MAXB; ++i) {
    if (ax[i] >= 0) ssort[nstart[ax[i] >> 13] + (ax[i] & 0x1FFF)] = rc[i];
  }
  __syncthreads();

  // coalesced write-back + global-indexed CSR metadata
  const int T = gend - b0;
  for (int j2 = t; j2 < T; j2 += 512) recs[b0 + j2] = ssort[j2];
  if (t < BKN) {
    const int n2 = kb * BKN + t;
    node_off[n2] = b0 + nstart[t];
    node_cnt[n2] = hist[t];
  }

  // aggregation: 4 lanes/node; quad = (edge-parity<<1)|channel-half
  const int quad = t & 3;
  const int half = quad & 1;
  const int epar = quad >> 1;
  const unsigned short* pb = p1h + half * 8;
#pragma unroll
  for (int p = 0; p < 2; ++p) {
    const int local = p * 128 + (t >> 2);
    if (local >= BKN) continue;  // quad-uniform branch
    const int n = kb * BKN + local;
    if (n >= N_NODES) continue;
    const int st = nstart[local];
    const int k = hist[local];

    float acc[8];
#pragma unroll
    for (int i = 0; i < 8; ++i) acc[i] = 0.f;
    int j = epar;
    for (; j + 6 < k; j += 8) {
      const int s0 = ssort[st + j], s1 = ssort[st + j + 2],
                s2 = ssort[st + j + 4], s3 = ssort[st + j + 6];
      const uint4 w0 = *(const uint4*)(pb + (size_t)s0 * 16);
      const uint4 w1 = *(const uint4*)(pb + (size_t)s1 * 16);
      const uint4 w2 = *(const uint4*)(pb + (size_t)s2 * 16);
      const uint4 w3 = *(const uint4*)(pb + (size_t)s3 * 16);
      acc[0] +=
          (bf2f_lo(w0.x) + bf2f_lo(w1.x)) + (bf2f_lo(w2.x) + bf2f_lo(w3.x));
      acc[1] +=
          (bf2f_hi(w0.x) + bf2f_hi(w1.x)) + (bf2f_hi(w2.x) + bf2f_hi(w3.x));
      acc[2] +=
          (bf2f_lo(w0.y) + bf2f_lo(w1.y)) + (bf2f_lo(w2.y) + bf2f_lo(w3.y));
      acc[3] +=
          (bf2f_hi(w0.y) + bf2f_hi(w1.y)) + (bf2f_hi(w2.y) + bf2f_hi(w3.y));
      acc[4] +=
          (bf2f_lo(w0.z) + bf2f_lo(w1.z)) + (bf2f_lo(w2.z) + bf2f_lo(w3.z));
      acc[5] +=
          (bf2f_hi(w0.z) + bf2f_hi(w1.z)) + (bf2f_hi(w2.z) + bf2f_hi(w3.z));
      acc[6] +=
          (bf2f_lo(w0.w) + bf2f_lo(w1.w)) + (bf2f_lo(w2.w) + bf2f_lo(w3.w));
      acc[7] +=
          (bf2f_hi(w0.w) + bf2f_hi(w1.w)) + (bf2f_hi(w2.w) + bf2f_hi(w3.w));
    }
    for (; j < k; j += 2) {
      const uint4 w = *(const uint4*)(pb + (size_t)ssort[st + j] * 16);
      acc[0] += bf2f_lo(w.x);
      acc[1] += bf2f_hi(w.x);
      acc[2] += bf2f_lo(w.y);
      acc[3] += bf2f_hi(w.y);
      acc[4] += bf2f_lo(w.z);
      acc[5] += bf2f_hi(w.z);
      acc[6] += bf2f_lo(w.w);
      acc[7] += bf2f_hi(w.w);
    }
#pragma unroll
    for (int i = 0; i < 8; ++i) acc[i] += __shfl_xor(acc[i], 2);

    const float di = 1.f / fmaxf((float)k, 1.f);
    const float4* qp = (const float4*)(q1b + (size_t)n * 16 + half * 8);
    const float4 qa = qp[0], qb = qp[1];
    float h[8];
    h[0] = fmaxf(fmaf(acc[0], di, qa.x), 0.f);
    h[1] = fmaxf(fmaf(acc[1], di, qa.y), 0.f);
    h[2] = fmaxf(fmaf(acc[2], di, qa.z), 0.f);
    h[3] = fmaxf(fmaf(acc[3], di, qa.w), 0.f);
    h[4] = fmaxf(fmaf(acc[4], di, qb.x), 0.f);
    h[5] = fmaxf(fmaf(acc[5], di, qb.y), 0.f);
    h[6] = fmaxf(fmaf(acc[6], di, qb.z), 0.f);
    h[7] = fmaxf(fmaf(acc[7], di, qb.w), 0.f);
    float pa = 0.f, pbv = 0.f;
#pragma unroll
    for (int i = 0; i < 8; ++i) {
      pa = fmaf(h[i], sWl[half * 8 + i], pa);
      pbv = fmaf(h[i], sWr[half * 8 + i], pbv);
    }
    pa += __shfl_xor(pa, 1);
    pbv += __shfl_xor(pbv, 1);
    if (quad == 0) {
      p2[n] = pa;
      r2[n] = pbv;
      deg_inv[n] = di;
    }
  }
}

// layer-2 aggregation + output epilogue: 768 blocks = exactly 3/CU (BKN=131
// geometry, two node passes), 4 lanes/node, register accumulation.
__global__ __launch_bounds__(512) void k_agg2out(
    const int* __restrict__ node_off, const int* __restrict__ node_cnt,
    const int* __restrict__ recs, const float* __restrict__ p2,
    const float* __restrict__ r2, const float* __restrict__ deg_inv,
    const float* __restrict__ b2, float* __restrict__ out) {
  const int t = threadIdx.x;
  const int kb = blockIdx.x;
  const int quad = t & 3;
#pragma unroll
  for (int p = 0; p < 2; ++p) {
    const int local = p * 128 + (t >> 2);
    if (local >= BKN) continue;  // quad-uniform branch
    const int n = kb * BKN + local;
    if (n >= N_NODES) continue;
    const int k0 = node_off[n];
    const int k = node_cnt[n];
    const int* sl = recs + k0;

    float u = 0.f;
    int j = quad;
    for (; j + 12 < k; j += 16) {
      const int sA = sl[j], sB = sl[j + 4], sC = sl[j + 8], sD = sl[j + 12];
      u += (p2[sA] + p2[sB]) + (p2[sC] + p2[sD]);
    }
    for (; j < k; j += 4) u += p2[sl[j]];
    u += __shfl_xor(u, 1);
    u += __shfl_xor(u, 2);
    if (quad == 0) out[n] = fmaf(u, deg_inv[n], r2[n] + b2[0]);
  }
}

extern "C" void kernel_launch(void* const* d_in, const int* in_sizes, int n_in,
                              void* d_out, int out_size, void* d_ws,
                              size_t ws_size, hipStream_t stream) {
  const float* x   = (const float*)d_in[0];
  const int*   ei  = (const int*)d_in[1];
  const float* Wl1 = (const float*)d_in[2];
  const float* Wr1 = (const float*)d_in[3];
  const float* b1  = (const float*)d_in[4];
  const float* Wl2 = (const float*)d_in[5];
  const float* Wr2 = (const float*)d_in[6];
  const float* b2  = (const float*)d_in[7];
  float* out = (float*)d_out;

  const size_t N = N_NODES;
  int* wi = (int*)d_ws;
  int* gcur     = wi;                                  // NB*16
  int* node_off = wi + NB * 16;                        // 100608
  int* node_cnt = node_off + 100608;                   // 100608
  int* recs     = node_cnt + 100608;                   // NB*RSZ
  unsigned short* p1h = (unsigned short*)(recs + (size_t)NB * RSZ);
  float* q1b     = (float*)(p1h + 16 * N);   // 16N ushorts = 8N words
  float* p2      = q1b + 16 * N;
  float* r2      = p2 + N;
  float* deg_inv = r2 + N;

  k_proj1<<<(N_NODES + 255) / 256, 256, 0, stream>>>(x, Wl1, Wr1, b1, p1h,
                                                     q1b, gcur);
  k_bscatter<<<NTILES, 512, 0, stream>>>(ei, gcur, recs);
  k_sortagg1<<<NB, 512, 0, stream>>>(gcur, recs, p1h, q1b, Wl2, Wr2, p2, r2,
                                     deg_inv, node_off, node_cnt);
  k_agg2out<<<NB, 512, 0, stream>>>(node_off, node_cnt, recs, p2, r2, deg_inv,
                                    b2, out);
}